// Round 25
// baseline (134.073 us; speedup 1.0000x reference)
//
#include <hip/hip_runtime.h>

typedef unsigned short u16;
typedef unsigned int u32;
typedef __bf16 bf16x8 __attribute__((ext_vector_type(8)));
typedef float f32x4 __attribute__((ext_vector_type(4)));
typedef u16   u16x8 __attribute__((ext_vector_type(8)));
typedef u32   u32x4 __attribute__((ext_vector_type(4)));

__device__ __forceinline__ u16 f2bf(float f) {
  __bf16 b = (__bf16)f;
  return __builtin_bit_cast(u16, b);
}
__device__ __forceinline__ float bf2f(u16 u) {
  unsigned int x = ((unsigned int)u) << 16;
  return __builtin_bit_cast(float, x);
}

// async global->LDS, 16B per lane. LDS dest: wave-uniform base + lane*16.
__device__ __forceinline__ void gll16(const u16* g, u16* l) {
  __builtin_amdgcn_global_load_lds(
      (const __attribute__((address_space(1))) void*)g,
      (__attribute__((address_space(3))) void*)l, 16, 0, 0);
}

// ---------------- merged f32 -> bf16 conversion (weights + activations) -----
__global__ __launch_bounds__(256) void convall_kernel(
    const float* __restrict__ s0, const float* __restrict__ s1,
    const float* __restrict__ s2, const float* __restrict__ s3,
    const float* __restrict__ s4, const float* __restrict__ s5,
    const float* __restrict__ s6,
    u16* __restrict__ o0, u16* __restrict__ o1, u16* __restrict__ o2,
    u16* __restrict__ o3, u16* __restrict__ o4, u16* __restrict__ o5,
    u16* __restrict__ o6)
{
  const int z = blockIdx.z;
  const float* s = (z == 0) ? s0 : (z == 1) ? s1 : (z == 2) ? s2 :
                   (z == 3) ? s3 : (z == 4) ? s4 : (z == 5) ? s5 : s6;
  u16* o = (z == 0) ? o0 : (z == 1) ? o1 : (z == 2) ? o2 :
           (z == 3) ? o3 : (z == 4) ? o4 : (z == 5) ? o5 : o6;
  const long n = (z < 4) ? (1l << 20) : 4096000l;
  const long i = ((long)blockIdx.x * 256 + threadIdx.x) * 8;
  if (i >= n) return;
  f32x4 a = *(const f32x4*)(s + i);
  f32x4 b = *(const f32x4*)(s + i + 4);
  u16x8 r;
#pragma unroll
  for (int e = 0; e < 4; ++e) { r[e] = f2bf(a[e]); r[e + 4] = f2bf(b[e]); }
  *(u16x8*)(o + i) = r;
}

// ---------------- MFMA GEMM (r13 config — fastest measured) -----------------
template<int BM, int OUT_F32>
__global__ __launch_bounds__(256, 3) void gemm_swz(
    const u16* __restrict__ A0, const u16* __restrict__ A1, const u16* __restrict__ A2,
    const u16* __restrict__ B0, const u16* __restrict__ B1, const u16* __restrict__ B2,
    const float* __restrict__ g0, const float* __restrict__ g1, const float* __restrict__ g2,
    void* __restrict__ C0, void* __restrict__ C1, void* __restrict__ C2, int Mvalid)
{
  constexpr int ACH = BM / 32;
  constexpr int MI  = BM / 32;
  const int z = blockIdx.z;
  const u16* Ab = (z == 0) ? A0 : (z == 1) ? A1 : A2;
  const u16* Bw = (z == 0) ? B0 : (z == 1) ? B1 : B2;
  const float* bias = (z == 0) ? g0 : (z == 1) ? g1 : g2;
  void* Cout = (z == 0) ? C0 : (z == 1) ? C1 : C2;

  __shared__ __align__(16) u16 As[BM * 64];
  __shared__ __align__(16) u16 Bs[128 * 64];

  const int tid = threadIdx.x;
  const int wid = tid >> 6, lane = tid & 63, ln = lane & 15, lg = lane >> 4;
  const int row0 = blockIdx.x * BM, col0 = blockIdx.y * 128;
  const int wr = (wid >> 1) * (BM / 2), wc = (wid & 1) * 64;
  const int lr8 = lane >> 3;
  const int kslot = 8 * ((lane & 7) ^ lr8);

  f32x4 acc[MI][4] = {};

  for (int kt = 0; kt < 16; ++kt) {
    const int k0 = kt * 64;
    __syncthreads();
#pragma unroll
    for (int c = 0; c < ACH; ++c) {
      int base = wid * (8 * ACH) + c * 8;
      long gr = row0 + base + lr8; if (gr >= Mvalid) gr = Mvalid - 1;
      gll16(Ab + gr * 1024 + k0 + kslot, &As[base * 64]);
    }
#pragma unroll
    for (int c = 0; c < 4; ++c) {
      int base = wid * 32 + c * 8;
      gll16(Bw + (long)(col0 + base + lr8) * 1024 + k0 + kslot, &Bs[base * 64]);
    }
    __syncthreads();

#pragma unroll
    for (int kk = 0; kk < 64; kk += 32) {
      bf16x8 af[MI], bfr[4];
#pragma unroll
      for (int i = 0; i < MI; ++i) {
        int r = wr + i * 16 + ln;
        af[i] = *(const bf16x8*)&As[r * 64 + ((kk + 8 * lg) ^ ((r & 7) << 3))];
      }
#pragma unroll
      for (int j = 0; j < 4; ++j) {
        int r = wc + j * 16 + ln;
        bfr[j] = *(const bf16x8*)&Bs[r * 64 + ((kk + 8 * lg) ^ ((r & 7) << 3))];
      }
#pragma unroll
      for (int i = 0; i < MI; ++i)
#pragma unroll
        for (int j = 0; j < 4; ++j)
          acc[i][j] = __builtin_amdgcn_mfma_f32_16x16x32_bf16(af[i], bfr[j], acc[i][j], 0, 0, 0);
    }
  }

  float bj[4];
#pragma unroll
  for (int j = 0; j < 4; ++j) bj[j] = bias[col0 + wc + j * 16 + ln];
#pragma unroll
  for (int i = 0; i < MI; ++i)
#pragma unroll
    for (int j = 0; j < 4; ++j)
#pragma unroll
      for (int reg = 0; reg < 4; ++reg) {
        int r = row0 + wr + i * 16 + 4 * lg + reg;
        int c = col0 + wc + j * 16 + ln;
        if (r < Mvalid) {
          float v = acc[i][j][reg] + bj[j];
          if constexpr (OUT_F32) ((float*)Cout)[(long)r * 1024 + c] = v;
          else                   ((u16*)Cout)[(long)r * 1024 + c] = f2bf(v);
        }
      }
}

// ---------------- MFMA flash attention v10 ----------------------------------
// v9 (r24 green: swapped QK^T + pairing + XCD map + fixed-M) with the P
// handoff moved from LDS to REGISTER SHUFFLES: lane (ln,lg) holds
// P[ln][16j+4lg+reg] as W0[j],W1[j]; PV A-frag words come from lanes
// src0=ln+32*(lg&1), src1=src0+16 at j_s=kk/16+(lg>>1). Removes 4 ds_write +
// lgkmcnt(0) fence + 2 ds_read per iteration (the pass-2 serial RAW point).
__global__ __launch_bounds__(256) void MaskedMultiheadAttention_51591147160164_kernel(
    const u16* __restrict__ Qb, const u16* __restrict__ Kb,
    const u16* __restrict__ Vb, const int* __restrict__ maskp,
    float* __restrict__ Aout, u16* __restrict__ ctx, float* __restrict__ dumpf)
{
  __shared__ __align__(16) u16 Qs[64 * 72];
  __shared__ __align__(16) u16 Ks[2][64 * 64];
  __shared__ __align__(16) u16 Vs[64 * 72];     // V^T tile [d=64][key=64]+pad
  __shared__ __align__(16) float Bf[1024];      // mask bias: 0 or -1e30

  const int bh = blockIdx.x;                    // XCD = bh%8 (K/V L2 sharing)
  const int b = bh >> 4, h = bh & 15;
  const int tid = threadIdx.x;
  const int wid = tid >> 6, lane = tid & 63, ln = lane & 15, lg = lane >> 4;

  // ---- mask bias: qb-independent, staged once ----
  {
    f32x4 bv;
#pragma unroll
    for (int e = 0; e < 4; ++e) {
      int ki = tid * 4 + e;
      int mv = (ki < 1000) ? maskp[b * 1000 + ki] : 0;
      bv[e] = mv ? 0.f : -1.0e30f;
    }
    *(f32x4*)&Bf[tid * 4] = bv;
  }

  const int lr8 = lane >> 3;
  const int kslot = 8 * ((lane & 7) ^ lr8);     // pre-swizzled source offset
  const long rowb = (long)b * 1000;
  const int vr = tid >> 2, vseg = tid & 3;      // V: 64 rows x 4 segs(16 u16)
  const float MREF = 16.0f;                     // fixed softmax reference
  const int psrc0 = ln + 32 * (lg & 1);         // P-exchange source lanes
  const int psrc1 = psrc0 + 16;
  const int phi = lg >> 1;                      // j_s select

  for (int half = 0; half < 2; ++half) {
    const int qb = half ? (15 - blockIdx.y) : blockIdx.y;
    const int q0 = qb * 64;
    const int nkt = qb + 1;                     // 64-wide k-tiles
    const int q = q0 + wid * 16 + ln;           // this lane's q row (swapped)

    // ---- stage Q (64x64) ----
    __syncthreads();                            // prev half LDS reads done / Bf ready
#pragma unroll
    for (int p = 0; p < 2; ++p) {
      int idx = p * 256 + tid;
      int r = idx >> 3, u = idx & 7;
      int tok = q0 + r; if (tok > 999) tok = 999;
      *(u16x8*)&Qs[r * 72 + u * 8] =
          *(const u16x8*)(Qb + (long)(b * 1000 + tok) * 1024 + h * 64 + u * 8);
    }
    __syncthreads();

    bf16x8 qf0, qf1;
    {
      int r = wid * 16 + ln;
      qf0 = *(const bf16x8*)&Qs[r * 72 +      8 * lg];
      qf1 = *(const bf16x8*)&Qs[r * 72 + 32 + 8 * lg];
    }
    __syncthreads();                            // Q consumed

    auto stageK = [&](int buf, int kt) {
#pragma unroll
      for (int c = 0; c < 2; ++c) {
        int r = wid * 16 + c * 8;
        gll16(Kb + (rowb + kt * 64 + r + lr8) * 1024 + h * 64 + kslot, &Ks[buf][r * 64]);
      }
    };
    auto loadV = [&](int kt, u16x8& ra, u16x8& rb) {
      const u16* s = Vb + (rowb + kt * 64 + vr) * 1024 + h * 64 + vseg * 16;
      ra = *(const u16x8*)s; rb = *(const u16x8*)(s + 8);
    };
    auto writeV = [&](const u16x8& ra, const u16x8& rb) {
#pragma unroll
      for (int e = 0; e < 8; ++e) Vs[(vseg * 16 + e) * 72 + vr] = ra[e];
#pragma unroll
      for (int e = 0; e < 8; ++e) Vs[(vseg * 16 + 8 + e) * 72 + vr] = rb[e];
    };
    // swapped: mfma(K, Q) -> D col=ln=q, row=4lg+reg=ki (within j-subtile)
    auto computeS = [&](int buf, f32x4 sf[4]) {
#pragma unroll
      for (int j = 0; j < 4; ++j) {
        int r = j * 16 + ln;
        int sw = (r & 7) << 3;
        bf16x8 kf0 = *(const bf16x8*)&Ks[buf][r * 64 + ((     8 * lg) ^ sw)];
        bf16x8 kf1 = *(const bf16x8*)&Ks[buf][r * 64 + ((32 + 8 * lg) ^ sw)];
        f32x4 z = {0.f, 0.f, 0.f, 0.f};
        z = __builtin_amdgcn_mfma_f32_16x16x32_bf16(kf0, qf0, z, 0, 0, 0);
        z = __builtin_amdgcn_mfma_f32_16x16x32_bf16(kf1, qf1, z, 0, 0, 0);
        sf[j] = z;
      }
    };

    // ---------- pass 1: denom only (fixed-M) ----------
    float lsum = 0.f;
    stageK(0, 0); stageK(1, 1);
    for (int t = 0; t < nkt; ++t) {
      const int buf = t & 1;
      if (t == 0 || t + 1 < nkt) asm volatile("s_waitcnt vmcnt(2)" ::: "memory");
      else                       asm volatile("s_waitcnt vmcnt(0)" ::: "memory");
      __builtin_amdgcn_sched_barrier(0);
      __builtin_amdgcn_s_barrier();             // tile t visible to all waves

      f32x4 sf[4]; computeS(buf, sf);
#pragma unroll
      for (int j = 0; j < 4; ++j) {
        int kb = t * 64 + j * 16 + 4 * lg;
        f32x4 b4 = *(const f32x4*)&Bf[kb];
#pragma unroll
        for (int reg = 0; reg < 4; ++reg) {
          float s = sf[j][reg] * 0.125f + b4[reg];
          s = (kb + reg <= q) ? s : -1.0e30f;
          lsum += __expf(s - MREF);
        }
      }
      __builtin_amdgcn_s_barrier();             // reads done before restage
      if (t + 2 < nkt) stageK(buf, t + 2);
    }
    lsum += __shfl_xor(lsum, 16);
    lsum += __shfl_xor(lsum, 32);
    const float rl = (lsum > 0.f) ? 1.0f / lsum : 0.f;

    // ---------- pass 2: normalized A + PV (register P-exchange) ----------
    f32x4 cacc[4] = {};

    u16x8 va0, va1, vb0, vb1;
    stageK(0, 0); loadV(0, va0, va1);
    stageK(1, 1); loadV(1, vb0, vb1);
    for (int t = 0; t < nkt; ++t) {
      const int buf = t & 1;
      // exact per-iter VMEM: 4 stores + 2 gll + 2 V loads.
      // steady: newer than tile-t loads = 4 stores(t-1) + 4 loads(t+1) = 8.
      if (t == 0 || t + 1 == nkt) asm volatile("s_waitcnt vmcnt(4)" ::: "memory");
      else                        asm volatile("s_waitcnt vmcnt(8)" ::: "memory");
      __builtin_amdgcn_sched_barrier(0);
      if (t & 1) writeV(vb0, vb1); else writeV(va0, va1);
      asm volatile("s_waitcnt lgkmcnt(0)" ::: "memory");
      __builtin_amdgcn_sched_barrier(0);
      __builtin_amdgcn_s_barrier();             // K(t) + V(t) staged for all

      f32x4 sf[4]; computeS(buf, sf);
      const long arow = ((long)bh * 1000 + q) * 1000;
      u32 W0[4], W1[4];                         // packed P: W0=cols 4g+0,1 W1=+2,3
#pragma unroll
      for (int j = 0; j < 4; ++j) {
        int kb = t * 64 + j * 16 + 4 * lg;
        f32x4 b4 = *(const f32x4*)&Bf[kb];
        f32x4 pv4;
#pragma unroll
        for (int reg = 0; reg < 4; ++reg) {
          float s = sf[j][reg] * 0.125f + b4[reg];
          s = (kb + reg <= q) ? s : -1.0e30f;
          pv4[reg] = __expf(s - MREF) * rl;
        }
        // unconditional vector A-store (clamped addr -> exact vmcnt accounting)
        float* dst = (q < 1000 && kb < 1000) ? (float*)&Aout[arow + kb]
                                             : dumpf + tid * 4;
        *(f32x4*)dst = pv4;
        W0[j] = (u32)f2bf(pv4[0]) | ((u32)f2bf(pv4[1]) << 16);
        W1[j] = (u32)f2bf(pv4[2]) | ((u32)f2bf(pv4[3]) << 16);
      }

      // PV with in-register P exchange (no LDS, no fences)
#pragma unroll
      for (int kk = 0; kk < 64; kk += 32) {
        const int jlo = kk / 16, jhi = jlo + 1;
        u32 a0 = (u32)__shfl((int)W0[jlo], psrc0, 64);
        u32 a1 = (u32)__shfl((int)W1[jlo], psrc0, 64);
        u32 a2 = (u32)__shfl((int)W0[jlo], psrc1, 64);
        u32 a3 = (u32)__shfl((int)W1[jlo], psrc1, 64);
        u32 b0 = (u32)__shfl((int)W0[jhi], psrc0, 64);
        u32 b1 = (u32)__shfl((int)W1[jhi], psrc0, 64);
        u32 b2 = (u32)__shfl((int)W0[jhi], psrc1, 64);
        u32 b3 = (u32)__shfl((int)W1[jhi], psrc1, 64);
        u32x4 pw;
        pw[0] = phi ? b0 : a0;
        pw[1] = phi ? b1 : a1;
        pw[2] = phi ? b2 : a2;
        pw[3] = phi ? b3 : a3;
        bf16x8 pf = __builtin_bit_cast(bf16x8, pw);
#pragma unroll
        for (int jn = 0; jn < 4; ++jn) {
          bf16x8 vf = *(const bf16x8*)&Vs[(jn * 16 + ln) * 72 + kk + 8 * lg];
          cacc[jn] = __builtin_amdgcn_mfma_f32_16x16x32_bf16(pf, vf, cacc[jn], 0, 0, 0);
        }
      }
      __builtin_amdgcn_s_barrier();             // Ks/Vs reads done
      if (t + 2 < nkt) {
        stageK(buf, t + 2);
        if (t & 1) loadV(t + 2, vb0, vb1); else loadV(t + 2, va0, va1);
      }
    }
    asm volatile("s_waitcnt vmcnt(0)" ::: "memory");  // drain tail stores/overstage

    const int qrow = q0 + wid * 16 + 4 * lg;    // D-layout rows for ctx
#pragma unroll
    for (int jn = 0; jn < 4; ++jn)
#pragma unroll
      for (int reg = 0; reg < 4; ++reg) {
        int qi = qrow + reg;
        if (qi < 1000)
          ctx[(long)(b * 1000 + qi) * 1024 + h * 64 + jn * 16 + ln] = f2bf(cacc[jn][reg]);
      }
  }
}

// ---------------- launch ----------------------------------------------------
extern "C" void kernel_launch(void* const* d_in, const int* in_sizes, int n_in,
                              void* d_out, int out_size, void* d_ws, size_t ws_size,
                              hipStream_t stream)
{
  const float* q  = (const float*)d_in[0];
  const float* k  = (const float*)d_in[1];
  const float* v  = (const float*)d_in[2];
  const int*  msk = (const int*)d_in[3];
  const float* Wq = (const float*)d_in[4];
  const float* bq = (const float*)d_in[5];
  const float* Wk = (const float*)d_in[6];
  const float* bk = (const float*)d_in[7];
  const float* Wv = (const float*)d_in[8];
  const float* bv = (const float*)d_in[9];
  const float* Wp = (const float*)d_in[10];
  const float* bp = (const float*)d_in[11];

  u16* ws  = (u16*)d_ws;                     // ~57.6 MB total
  u16* Qc  = ws;                             // [4000][1024] bf16 (ctx aliases later)
  u16* Kc  = ws + 4096000u;
  u16* Vc  = ws + 2u * 4096000u;
  u16* Qb  = ws + 3u * 4096000u;
  u16* Kb  = ws + 4u * 4096000u;
  u16* Vb  = ws + 5u * 4096000u;
  u16* wqb = ws + 6u * 4096000u;
  u16* wkb = wqb + (1u << 20);
  u16* wvb = wkb + (1u << 20);
  u16* wpb = wvb + (1u << 20);
  float* dumpf = (float*)(wpb + (1u << 20)); // 4KB spill target for clamped stores
  u16* ctx = Qc;

  float* Xout = (float*)d_out;               // [4000][1024] f32 (output x)
  float* Aout = Xout + 4096000;              // [64][1000][1000] f32 (output A)

  convall_kernel<<<dim3(2000, 1, 7), 256, 0, stream>>>(
      Wq, Wk, Wv, Wp, q, k, v,
      wqb, wkb, wvb, wpb, Qc, Kc, Vc);
  gemm_swz<128, 0><<<dim3(32, 8, 3), 256, 0, stream>>>(
      Qc, Kc, Vc, wqb, wkb, wvb, bq, bk, bv, Qb, Kb, Vb, 4000);
  // grid (bh=64, pair=8): XCD = linear%8 = bh%8 -> K/V L2-shared per head
  MaskedMultiheadAttention_51591147160164_kernel<<<dim3(64, 8), 256, 0, stream>>>(
      Qb, Kb, Vb, msk, Aout, ctx, dumpf);
  gemm_swz<64, 1><<<dim3(63, 8, 1), 256, 0, stream>>>(
      ctx, ctx, ctx, wpb, wpb, wpb, bp, bp, bp, Xout, Xout, Xout, 4000);
}

// Round 26
// 130.284 us; speedup vs baseline: 1.0291x; 1.0291x over previous
//
#include <hip/hip_runtime.h>

typedef unsigned short u16;
typedef unsigned int u32;
typedef __bf16 bf16x8 __attribute__((ext_vector_type(8)));
typedef float f32x4 __attribute__((ext_vector_type(4)));
typedef u16   u16x8 __attribute__((ext_vector_type(8)));

__device__ __forceinline__ u16 f2bf(float f) {
  __bf16 b = (__bf16)f;
  return __builtin_bit_cast(u16, b);
}
__device__ __forceinline__ float bf2f(u16 u) {
  unsigned int x = ((unsigned int)u) << 16;
  return __builtin_bit_cast(float, x);
}

// async global->LDS, 16B per lane. LDS dest: wave-uniform base + lane*16.
__device__ __forceinline__ void gll16(const u16* g, u16* l) {
  __builtin_amdgcn_global_load_lds(
      (const __attribute__((address_space(1))) void*)g,
      (__attribute__((address_space(3))) void*)l, 16, 0, 0);
}

// ---------------- merged f32 -> bf16 conversion (weights + activations) -----
__global__ __launch_bounds__(256) void convall_kernel(
    const float* __restrict__ s0, const float* __restrict__ s1,
    const float* __restrict__ s2, const float* __restrict__ s3,
    const float* __restrict__ s4, const float* __restrict__ s5,
    const float* __restrict__ s6,
    u16* __restrict__ o0, u16* __restrict__ o1, u16* __restrict__ o2,
    u16* __restrict__ o3, u16* __restrict__ o4, u16* __restrict__ o5,
    u16* __restrict__ o6)
{
  const int z = blockIdx.z;
  const float* s = (z == 0) ? s0 : (z == 1) ? s1 : (z == 2) ? s2 :
                   (z == 3) ? s3 : (z == 4) ? s4 : (z == 5) ? s5 : s6;
  u16* o = (z == 0) ? o0 : (z == 1) ? o1 : (z == 2) ? o2 :
           (z == 3) ? o3 : (z == 4) ? o4 : (z == 5) ? o5 : o6;
  const long n = (z < 4) ? (1l << 20) : 4096000l;
  const long i = ((long)blockIdx.x * 256 + threadIdx.x) * 8;
  if (i >= n) return;
  f32x4 a = *(const f32x4*)(s + i);
  f32x4 b = *(const f32x4*)(s + i + 4);
  u16x8 r;
#pragma unroll
  for (int e = 0; e < 4; ++e) { r[e] = f2bf(a[e]); r[e + 4] = f2bf(b[e]); }
  *(u16x8*)(o + i) = r;
}

// ---------------- MFMA GEMM (r13 config — fastest measured) -----------------
template<int BM, int OUT_F32>
__global__ __launch_bounds__(256, 3) void gemm_swz(
    const u16* __restrict__ A0, const u16* __restrict__ A1, const u16* __restrict__ A2,
    const u16* __restrict__ B0, const u16* __restrict__ B1, const u16* __restrict__ B2,
    const float* __restrict__ g0, const float* __restrict__ g1, const float* __restrict__ g2,
    void* __restrict__ C0, void* __restrict__ C1, void* __restrict__ C2, int Mvalid)
{
  constexpr int ACH = BM / 32;
  constexpr int MI  = BM / 32;
  const int z = blockIdx.z;
  const u16* Ab = (z == 0) ? A0 : (z == 1) ? A1 : A2;
  const u16* Bw = (z == 0) ? B0 : (z == 1) ? B1 : B2;
  const float* bias = (z == 0) ? g0 : (z == 1) ? g1 : g2;
  void* Cout = (z == 0) ? C0 : (z == 1) ? C1 : C2;

  __shared__ __align__(16) u16 As[BM * 64];
  __shared__ __align__(16) u16 Bs[128 * 64];

  const int tid = threadIdx.x;
  const int wid = tid >> 6, lane = tid & 63, ln = lane & 15, lg = lane >> 4;
  const int row0 = blockIdx.x * BM, col0 = blockIdx.y * 128;
  const int wr = (wid >> 1) * (BM / 2), wc = (wid & 1) * 64;
  const int lr8 = lane >> 3;
  const int kslot = 8 * ((lane & 7) ^ lr8);

  f32x4 acc[MI][4] = {};

  for (int kt = 0; kt < 16; ++kt) {
    const int k0 = kt * 64;
    __syncthreads();
#pragma unroll
    for (int c = 0; c < ACH; ++c) {
      int base = wid * (8 * ACH) + c * 8;
      long gr = row0 + base + lr8; if (gr >= Mvalid) gr = Mvalid - 1;
      gll16(Ab + gr * 1024 + k0 + kslot, &As[base * 64]);
    }
#pragma unroll
    for (int c = 0; c < 4; ++c) {
      int base = wid * 32 + c * 8;
      gll16(Bw + (long)(col0 + base + lr8) * 1024 + k0 + kslot, &Bs[base * 64]);
    }
    __syncthreads();

#pragma unroll
    for (int kk = 0; kk < 64; kk += 32) {
      bf16x8 af[MI], bfr[4];
#pragma unroll
      for (int i = 0; i < MI; ++i) {
        int r = wr + i * 16 + ln;
        af[i] = *(const bf16x8*)&As[r * 64 + ((kk + 8 * lg) ^ ((r & 7) << 3))];
      }
#pragma unroll
      for (int j = 0; j < 4; ++j) {
        int r = wc + j * 16 + ln;
        bfr[j] = *(const bf16x8*)&Bs[r * 64 + ((kk + 8 * lg) ^ ((r & 7) << 3))];
      }
#pragma unroll
      for (int i = 0; i < MI; ++i)
#pragma unroll
        for (int j = 0; j < 4; ++j)
          acc[i][j] = __builtin_amdgcn_mfma_f32_16x16x32_bf16(af[i], bfr[j], acc[i][j], 0, 0, 0);
    }
  }

  float bj[4];
#pragma unroll
  for (int j = 0; j < 4; ++j) bj[j] = bias[col0 + wc + j * 16 + ln];
#pragma unroll
  for (int i = 0; i < MI; ++i)
#pragma unroll
    for (int j = 0; j < 4; ++j)
#pragma unroll
      for (int reg = 0; reg < 4; ++reg) {
        int r = row0 + wr + i * 16 + 4 * lg + reg;
        int c = col0 + wc + j * 16 + ln;
        if (r < Mvalid) {
          float v = acc[i][j][reg] + bj[j];
          if constexpr (OUT_F32) ((float*)Cout)[(long)r * 1024 + c] = v;
          else                   ((u16*)Cout)[(long)r * 1024 + c] = f2bf(v);
        }
      }
}

// ---------------- MFMA flash attention v11 ----------------------------------
// Pass 2 = r24-green exactly (LDS P handoff; shfl variant regressed).
// Pass 1 = KVBLK=128: Ks dbuf widened to [2][128*64]; 4 gll/wave per stage;
// ~half the barriers/waits. Overshoot keys >=1000 are discarded by the
// causal/mask SELECT before use (NaN-safe); reads stay inside d_ws.
__global__ __launch_bounds__(256) void MaskedMultiheadAttention_51591147160164_kernel(
    const u16* __restrict__ Qb, const u16* __restrict__ Kb,
    const u16* __restrict__ Vb, const int* __restrict__ maskp,
    float* __restrict__ Aout, u16* __restrict__ ctx, float* __restrict__ dumpf)
{
  __shared__ __align__(16) u16 QsPs[64 * 72];   // Qs (prologue) then Ps (pass 2)
  __shared__ __align__(16) u16 Ks[2][128 * 64]; // pass1: 128-key tiles; pass2: rows 0..63
  __shared__ __align__(16) u16 Vs[64 * 72];     // V^T tile [d=64][key=64]+pad
  __shared__ __align__(16) float Bf[1024];      // mask bias: 0 or -1e30

  const int bh = blockIdx.x;                    // XCD = bh%8 (K/V L2 sharing)
  const int b = bh >> 4, h = bh & 15;
  const int tid = threadIdx.x;
  const int wid = tid >> 6, lane = tid & 63, ln = lane & 15, lg = lane >> 4;

  // ---- mask bias: qb-independent, staged once ----
  {
    f32x4 bv;
#pragma unroll
    for (int e = 0; e < 4; ++e) {
      int ki = tid * 4 + e;
      int mv = (ki < 1000) ? maskp[b * 1000 + ki] : 0;
      bv[e] = mv ? 0.f : -1.0e30f;
    }
    *(f32x4*)&Bf[tid * 4] = bv;
  }

  const int lr8 = lane >> 3;
  const int kslot = 8 * ((lane & 7) ^ lr8);     // pre-swizzled source offset
  const long rowb = (long)b * 1000;
  const int vr = tid >> 2, vseg = tid & 3;      // V: 64 rows x 4 segs(16 u16)
  const float MREF = 16.0f;                     // fixed softmax reference

  for (int half = 0; half < 2; ++half) {
    const int qb = half ? (15 - blockIdx.y) : blockIdx.y;
    const int q0 = qb * 64;
    const int nkt = qb + 1;                     // 64-wide k-tiles
    const int q = q0 + wid * 16 + ln;           // this lane's q row (swapped)

    // ---- stage Q (64x64) ----
    __syncthreads();                            // prev half LDS reads done / Bf ready
#pragma unroll
    for (int p = 0; p < 2; ++p) {
      int idx = p * 256 + tid;
      int r = idx >> 3, u = idx & 7;
      int tok = q0 + r; if (tok > 999) tok = 999;
      *(u16x8*)&QsPs[r * 72 + u * 8] =
          *(const u16x8*)(Qb + (long)(b * 1000 + tok) * 1024 + h * 64 + u * 8);
    }
    __syncthreads();

    bf16x8 qf0, qf1;
    {
      int r = wid * 16 + ln;
      qf0 = *(const bf16x8*)&QsPs[r * 72 +      8 * lg];
      qf1 = *(const bf16x8*)&QsPs[r * 72 + 32 + 8 * lg];
    }
    __syncthreads();                            // Q consumed before Ps reuse

    auto stageK = [&](int buf, int kt) {        // 64-key stage (pass 2)
#pragma unroll
      for (int c = 0; c < 2; ++c) {
        int r = wid * 16 + c * 8;
        gll16(Kb + (rowb + kt * 64 + r + lr8) * 1024 + h * 64 + kslot, &Ks[buf][r * 64]);
      }
    };
    auto stageK128 = [&](int buf, int t) {      // 128-key stage (pass 1)
#pragma unroll
      for (int c = 0; c < 4; ++c) {
        int r = wid * 32 + c * 8;
        gll16(Kb + (rowb + t * 128 + r + lr8) * 1024 + h * 64 + kslot, &Ks[buf][r * 64]);
      }
    };
    auto loadV = [&](int kt, u16x8& ra, u16x8& rb) {
      const u16* s = Vb + (rowb + kt * 64 + vr) * 1024 + h * 64 + vseg * 16;
      ra = *(const u16x8*)s; rb = *(const u16x8*)(s + 8);
    };
    auto writeV = [&](const u16x8& ra, const u16x8& rb) {
#pragma unroll
      for (int e = 0; e < 8; ++e) Vs[(vseg * 16 + e) * 72 + vr] = ra[e];
#pragma unroll
      for (int e = 0; e < 8; ++e) Vs[(vseg * 16 + 8 + e) * 72 + vr] = rb[e];
    };
    // swapped: mfma(K, Q) -> D col=ln=q, row=4lg+reg=ki (within j-subtile)
    auto computeS = [&](int buf, f32x4 sf[4]) {
#pragma unroll
      for (int j = 0; j < 4; ++j) {
        int r = j * 16 + ln;
        int sw = (r & 7) << 3;
        bf16x8 kf0 = *(const bf16x8*)&Ks[buf][r * 64 + ((     8 * lg) ^ sw)];
        bf16x8 kf1 = *(const bf16x8*)&Ks[buf][r * 64 + ((32 + 8 * lg) ^ sw)];
        f32x4 z = {0.f, 0.f, 0.f, 0.f};
        z = __builtin_amdgcn_mfma_f32_16x16x32_bf16(kf0, qf0, z, 0, 0, 0);
        z = __builtin_amdgcn_mfma_f32_16x16x32_bf16(kf1, qf1, z, 0, 0, 0);
        sf[j] = z;
      }
    };

    // ---------- pass 1: denom only (fixed-M), 128-key tiles ----------
    float lsum = 0.f;
    const int nt = (nkt + 1) >> 1;              // 128-wide tiles
    stageK128(0, 0); stageK128(1, 1);           // 8 gll in flight (uncond)
    for (int t = 0; t < nt; ++t) {
      const int buf = t & 1;
      if (t == 0 || t + 1 < nt) asm volatile("s_waitcnt vmcnt(4)" ::: "memory");
      else                      asm volatile("s_waitcnt vmcnt(0)" ::: "memory");
      __builtin_amdgcn_sched_barrier(0);
      __builtin_amdgcn_s_barrier();             // tile t visible to all waves

#pragma unroll
      for (int j = 0; j < 8; ++j) {
        int r = j * 16 + ln;
        int sw = (r & 7) << 3;
        bf16x8 kf0 = *(const bf16x8*)&Ks[buf][r * 64 + ((     8 * lg) ^ sw)];
        bf16x8 kf1 = *(const bf16x8*)&Ks[buf][r * 64 + ((32 + 8 * lg) ^ sw)];
        f32x4 z = {0.f, 0.f, 0.f, 0.f};
        z = __builtin_amdgcn_mfma_f32_16x16x32_bf16(kf0, qf0, z, 0, 0, 0);
        z = __builtin_amdgcn_mfma_f32_16x16x32_bf16(kf1, qf1, z, 0, 0, 0);
        int kb = t * 128 + j * 16 + 4 * lg;
        f32x4 b4 = *(const f32x4*)&Bf[kb];
#pragma unroll
        for (int reg = 0; reg < 4; ++reg) {
          float s = z[reg] * 0.125f + b4[reg];
          s = (kb + reg <= q) ? s : -1.0e30f;   // select discards garbage/NaN
          lsum += __expf(s - MREF);
        }
      }
      __builtin_amdgcn_s_barrier();             // reads done before restage
      if (t + 2 < nt) stageK128(buf, t + 2);
    }
    lsum += __shfl_xor(lsum, 16);
    lsum += __shfl_xor(lsum, 32);
    const float rl = (lsum > 0.f) ? 1.0f / lsum : 0.f;

    // ---------- pass 2: normalized A + PV (r24-green) ----------
    f32x4 cacc[4] = {};
    u16* Pw = &QsPs[wid * 16 * 72];             // per-wave P tile [16 q][72]

    u16x8 va0, va1, vb0, vb1;
    stageK(0, 0); loadV(0, va0, va1);
    stageK(1, 1); loadV(1, vb0, vb1);
    for (int t = 0; t < nkt; ++t) {
      const int buf = t & 1;
      // exact per-iter VMEM: 4 stores + 2 gll + 2 V loads.
      // steady: newer than tile-t loads = 4 stores(t-1) + 4 loads(t+1) = 8.
      if (t == 0 || t + 1 == nkt) asm volatile("s_waitcnt vmcnt(4)" ::: "memory");
      else                        asm volatile("s_waitcnt vmcnt(8)" ::: "memory");
      __builtin_amdgcn_sched_barrier(0);
      if (t & 1) writeV(vb0, vb1); else writeV(va0, va1);
      asm volatile("s_waitcnt lgkmcnt(0)" ::: "memory");
      __builtin_amdgcn_sched_barrier(0);
      __builtin_amdgcn_s_barrier();             // K(t) + V(t) staged for all

      f32x4 sf[4]; computeS(buf, sf);
      const long arow = ((long)bh * 1000 + q) * 1000;
#pragma unroll
      for (int j = 0; j < 4; ++j) {
        int kb = t * 64 + j * 16 + 4 * lg;
        f32x4 b4 = *(const f32x4*)&Bf[kb];
        f32x4 pv4;
#pragma unroll
        for (int reg = 0; reg < 4; ++reg) {
          float s = sf[j][reg] * 0.125f + b4[reg];
          s = (kb + reg <= q) ? s : -1.0e30f;
          pv4[reg] = __expf(s - MREF) * rl;
        }
        // unconditional vector A-store (clamped addr -> exact vmcnt accounting)
        float* dst = (q < 1000 && kb < 1000) ? (float*)&Aout[arow + kb]
                                             : dumpf + tid * 4;
        *(f32x4*)dst = pv4;
        // packed P write: 4 consecutive ki as 2 u32 (one b64 write)
        u32 w0 = (u32)f2bf(pv4[0]) | ((u32)f2bf(pv4[1]) << 16);
        u32 w1 = (u32)f2bf(pv4[2]) | ((u32)f2bf(pv4[3]) << 16);
        uint2 pk; pk.x = w0; pk.y = w1;
        *(uint2*)&Pw[ln * 72 + j * 16 + 4 * lg] = pk;
      }
      asm volatile("s_waitcnt lgkmcnt(0)" ::: "memory");  // Pw same-wave RAW
      __builtin_amdgcn_sched_barrier(0);
#pragma unroll
      for (int kk = 0; kk < 64; kk += 32) {
        bf16x8 pf = *(const bf16x8*)&Pw[ln * 72 + kk + 8 * lg];
#pragma unroll
        for (int jn = 0; jn < 4; ++jn) {
          bf16x8 vf = *(const bf16x8*)&Vs[(jn * 16 + ln) * 72 + kk + 8 * lg];
          cacc[jn] = __builtin_amdgcn_mfma_f32_16x16x32_bf16(pf, vf, cacc[jn], 0, 0, 0);
        }
      }
      __builtin_amdgcn_s_barrier();             // Ks/Vs reads done
      if (t + 2 < nkt) {
        stageK(buf, t + 2);
        if (t & 1) loadV(t + 2, vb0, vb1); else loadV(t + 2, va0, va1);
      }
    }
    asm volatile("s_waitcnt vmcnt(0)" ::: "memory");  // drain tail stores/overstage

    const int qrow = q0 + wid * 16 + 4 * lg;    // D-layout rows for ctx
#pragma unroll
    for (int jn = 0; jn < 4; ++jn)
#pragma unroll
      for (int reg = 0; reg < 4; ++reg) {
        int qi = qrow + reg;
        if (qi < 1000)
          ctx[(long)(b * 1000 + qi) * 1024 + h * 64 + jn * 16 + ln] = f2bf(cacc[jn][reg]);
      }
  }
}

// ---------------- launch ----------------------------------------------------
extern "C" void kernel_launch(void* const* d_in, const int* in_sizes, int n_in,
                              void* d_out, int out_size, void* d_ws, size_t ws_size,
                              hipStream_t stream)
{
  const float* q  = (const float*)d_in[0];
  const float* k  = (const float*)d_in[1];
  const float* v  = (const float*)d_in[2];
  const int*  msk = (const int*)d_in[3];
  const float* Wq = (const float*)d_in[4];
  const float* bq = (const float*)d_in[5];
  const float* Wk = (const float*)d_in[6];
  const float* bk = (const float*)d_in[7];
  const float* Wv = (const float*)d_in[8];
  const float* bv = (const float*)d_in[9];
  const float* Wp = (const float*)d_in[10];
  const float* bp = (const float*)d_in[11];

  u16* ws  = (u16*)d_ws;                     // ~57.6 MB total
  u16* Qc  = ws;                             // [4000][1024] bf16 (ctx aliases later)
  u16* Kc  = ws + 4096000u;
  u16* Vc  = ws + 2u * 4096000u;
  u16* Qb  = ws + 3u * 4096000u;
  u16* Kb  = ws + 4u * 4096000u;
  u16* Vb  = ws + 5u * 4096000u;
  u16* wqb = ws + 6u * 4096000u;
  u16* wkb = wqb + (1u << 20);
  u16* wvb = wkb + (1u << 20);
  u16* wpb = wvb + (1u << 20);
  float* dumpf = (float*)(wpb + (1u << 20)); // 4KB spill target for clamped stores
  u16* ctx = Qc;

  float* Xout = (float*)d_out;               // [4000][1024] f32 (output x)
  float* Aout = Xout + 4096000;              // [64][1000][1000] f32 (output A)

  convall_kernel<<<dim3(2000, 1, 7), 256, 0, stream>>>(
      Wq, Wk, Wv, Wp, q, k, v,
      wqb, wkb, wvb, wpb, Qc, Kc, Vc);
  gemm_swz<128, 0><<<dim3(32, 8, 3), 256, 0, stream>>>(
      Qc, Kc, Vc, wqb, wkb, wvb, bq, bk, bv, Qb, Kb, Vb, 4000);
  // grid (bh=64, pair=8): XCD = linear%8 = bh%8 -> K/V L2-shared per head
  MaskedMultiheadAttention_51591147160164_kernel<<<dim3(64, 8), 256, 0, stream>>>(
      Qb, Kb, Vb, msk, Aout, ctx, dumpf);
  gemm_swz<64, 1><<<dim3(63, 8, 1), 256, 0, stream>>>(
      ctx, ctx, ctx, wpb, wpb, wpb, bp, bp, bp, Xout, Xout, Xout, 4000);
}